// Round 1
// baseline (386.147 us; speedup 1.0000x reference)
//
#include <hip/hip_runtime.h>

#define NN 50000
#define NE 800000
#define ETOT (NE + NN)           // 850000 incl. self-loops
#define INCH 128
#define OUTC 64

// ---------------- workspace layout (bytes) ----------------
// hpair : float2[NN*64]            @ 0          (25,600,000 B)
// a_src : float2[NN]               @ 25,600,000 (400,000 B)
// a_dst : float2[NN]               @ 26,000,000 (400,000 B)
// wbuf  : float2[ETOT]             @ 26,400,000 (6,800,000 B)
// denom : float[2*NN]              @ 33,200,000 (400,000 B)
// total ~33.6 MB

#define OFF_HPAIR 0
#define OFF_ASRC  25600000
#define OFF_ADST  26000000
#define OFF_WBUF  26400000
#define OFF_DENOM 33200000

// out[n*64+c] = bias[c]; denom = 0
__global__ __launch_bounds__(256) void k_init(float* __restrict__ out,
                                              const float* __restrict__ bias,
                                              float* __restrict__ denom) {
    int i = blockIdx.x * 256 + threadIdx.x;
    if (i < NN * 64) out[i] = bias[i & 63];
    if (i < 2 * NN) denom[i] = 0.f;
}

// h = x @ W  (reshaped [N,2,64], stored interleaved float2(h0,h1)),
// plus attention dot products a_src[n][h], a_dst[n][h].
// 8 nodes / block of 256; thread (nl=tid>>5, lane=tid&31) computes cols
// lane, lane+32, lane+64, lane+96 of the 128-wide projection.
__global__ __launch_bounds__(256) void k_gemm(const float* __restrict__ x,
                                              const float* __restrict__ W,
                                              const float* __restrict__ att_src,
                                              const float* __restrict__ att_dst,
                                              float2* __restrict__ hpair,
                                              float2* __restrict__ asrc,
                                              float2* __restrict__ adst) {
    __shared__ float xs[8][INCH];
    const int tid = threadIdx.x;
    const int nbase = blockIdx.x * 8;

    // stage 8 x-rows (1024 floats) as 256 float4 loads
    const float4* xsrc = (const float4*)(x + (size_t)nbase * INCH);
    ((float4*)xs)[tid] = xsrc[tid];
    __syncthreads();

    const int nl = tid >> 5;
    const int lane = tid & 31;
    const int n = nbase + nl;

    float acc0 = 0.f, acc1 = 0.f, acc2 = 0.f, acc3 = 0.f;
    const float* xr = xs[nl];
#pragma unroll 8
    for (int k = 0; k < INCH; ++k) {
        const float xv = xr[k];
        const float* wr = W + k * 128;
        acc0 += xv * wr[lane];
        acc1 += xv * wr[lane + 32];
        acc2 += xv * wr[lane + 64];
        acc3 += xv * wr[lane + 96];
    }

    // h layout: head0 = cols 0..63, head1 = cols 64..127
    hpair[(size_t)n * 64 + lane]      = make_float2(acc0, acc2);
    hpair[(size_t)n * 64 + lane + 32] = make_float2(acc1, acc3);

    // partial attention dots (head0: acc0/acc1; head1: acc2/acc3)
    float ps0 = acc0 * att_src[lane]      + acc1 * att_src[lane + 32];
    float ps1 = acc2 * att_src[64 + lane] + acc3 * att_src[64 + lane + 32];
    float pd0 = acc0 * att_dst[lane]      + acc1 * att_dst[lane + 32];
    float pd1 = acc2 * att_dst[64 + lane] + acc3 * att_dst[64 + lane + 32];

#pragma unroll
    for (int m = 16; m >= 1; m >>= 1) {
        ps0 += __shfl_xor(ps0, m);
        ps1 += __shfl_xor(ps1, m);
        pd0 += __shfl_xor(pd0, m);
        pd1 += __shfl_xor(pd1, m);
    }
    if (lane == 0) {
        asrc[n] = make_float2(ps0, ps1);
        adst[n] = make_float2(pd0, pd1);
    }
}

// pass 1 over edges: w = exp(leaky_relu(a_src[s]+a_dst[d])), denom[d] += w
__global__ __launch_bounds__(256) void k_edge1(const int* __restrict__ ei,
                                               const float2* __restrict__ asrc,
                                               const float2* __restrict__ adst,
                                               float2* __restrict__ wbuf,
                                               float* __restrict__ denom) {
    int e = blockIdx.x * 256 + threadIdx.x;
    if (e >= ETOT) return;
    int s, d;
    if (e < NE) { s = ei[e]; d = ei[NE + e]; }
    else        { s = d = e - NE; }
    const float2 as = asrc[s];
    const float2 ad = adst[d];
    float v0 = as.x + ad.x;
    float v1 = as.y + ad.y;
    v0 = v0 > 0.f ? v0 : 0.2f * v0;
    v1 = v1 > 0.f ? v1 : 0.2f * v1;
    const float w0 = __expf(v0);
    const float w1 = __expf(v1);
    wbuf[e] = make_float2(w0, w1);
    atomicAdd(denom + 2 * d,     w0);
    atomicAdd(denom + 2 * d + 1, w1);
}

// pass 2: one 64-lane wave per edge, lane = output channel.
// out[d][c] += 0.5*(alpha0*h0[s][c] + alpha1*h1[s][c])
__global__ __launch_bounds__(256) void k_edge2(const int* __restrict__ ei,
                                               const float2* __restrict__ wbuf,
                                               const float* __restrict__ denom,
                                               const float2* __restrict__ hpair,
                                               float* __restrict__ out) {
    const int wid = (int)((blockIdx.x * 256 + threadIdx.x) >> 6);
    const int lane = threadIdx.x & 63;
    if (wid >= ETOT) return;
    int s, d;
    if (wid < NE) { s = ei[wid]; d = ei[NE + wid]; }
    else          { s = d = wid - NE; }
    const float2 w = wbuf[wid];
    const float2 dn = *(const float2*)(denom + 2 * d);
    const float a0 = w.x / dn.x;
    const float a1 = w.y / dn.y;
    const float2 h = hpair[(size_t)s * 64 + lane];
    const float val = 0.5f * (a0 * h.x + a1 * h.y);
    atomicAdd(out + (size_t)d * 64 + lane, val);
}

extern "C" void kernel_launch(void* const* d_in, const int* in_sizes, int n_in,
                              void* d_out, int out_size, void* d_ws, size_t ws_size,
                              hipStream_t stream) {
    const float* x       = (const float*)d_in[0];
    const float* W       = (const float*)d_in[1];
    const float* att_src = (const float*)d_in[2];
    const float* att_dst = (const float*)d_in[3];
    const float* bias    = (const float*)d_in[4];
    const int*   ei      = (const int*)d_in[5];
    float* out = (float*)d_out;

    char* ws = (char*)d_ws;
    float2* hpair = (float2*)(ws + OFF_HPAIR);
    float2* asrc  = (float2*)(ws + OFF_ASRC);
    float2* adst  = (float2*)(ws + OFF_ADST);
    float2* wbuf  = (float2*)(ws + OFF_WBUF);
    float*  denom = (float*)(ws + OFF_DENOM);

    // init out = bias, denom = 0
    {
        int total = NN * 64;
        int blocks = (total + 255) / 256;
        k_init<<<blocks, 256, 0, stream>>>(out, bias, denom);
    }
    // h = x@W + attention dots  (8 nodes/block)
    {
        int blocks = NN / 8;  // 50000 % 8 == 0
        k_gemm<<<blocks, 256, 0, stream>>>(x, W, att_src, att_dst, hpair, asrc, adst);
    }
    // edge pass 1: exp weights + denominators
    {
        int blocks = (ETOT + 255) / 256;
        k_edge1<<<blocks, 256, 0, stream>>>(ei, asrc, adst, wbuf, denom);
    }
    // edge pass 2: weighted scatter aggregation (1 wave per edge)
    {
        int waves_per_block = 4;
        int blocks = (ETOT + waves_per_block - 1) / waves_per_block;
        k_edge2<<<blocks, 256, 0, stream>>>(ei, wbuf, denom, hpair, out);
    }
}